// Round 5
// baseline (90.065 us; speedup 1.0000x reference)
//
#include <hip/hip_runtime.h>

// N=32, CIN=64, COUT=128, K=4, H=W=64
#define Nn     32
#define CIN    64
#define COUT   128
#define HWVOL  4096                 // H*W
#define PLANES (Nn * CIN)           // 2048 blocks, one x-plane each
#define SWVALS (CIN * COUT)         // 8192
#define OHW_INV (1.0f / 4489.0f)    // 1/67^2
#define NEGBIG (-3.0e38f)
#define MAGIC  0x5EC7A5A1u          // distinct bytes: no byte-pattern poison can match

// ---------------------------------------------------------------------------
// Single-dispatch, zero-fence fused kernel.
//   R2 lesson: agent __threadfence = whole-L2 writeback (~100us for 2048).
//   R4 lesson: 33KB LDS halved streaming occupancy; 262K fetch_add(0) RMWs
//              serialized the tail. Fixes: agent-scope atomic LOADS (coherent,
//              pipelined -- proven correct in R2's flag polls) and a
//              register/16KB-LDS split of Sw so LDS stays under the
//              8-blocks/CU budget (160/8 = 20 KB).
//
// Publish (unchanged, proven): each value is ONE packed u64 {MAGIC, bits}
// via agent-scope atomic exchange -- data+flag in a single word, no ordering
// needed, no fences.
//
// Block b (0..2047): sums x-plane b -> Sx64[b].
// Blocks 0..31 first compute a 256-value Sw chunk (exact R0 tree) -> Sw64.
// Consumers (blocks 0..31): thread t fetches Sw64[k*256+t], k=0..31, which is
// exactly (ci = 2k + (t>>7), co = t&127):
//   t <128 : even-ci values -> registers sw_reg[32]
//   t>=128 : odd-ci  values -> LDS sws_odd[k][co]
// Thread co then accumulates in EXACT ci = 0,1,2,...,63 order (even from reg,
// odd from LDS) -- bit-identical to the proven 79us kernel -- then logsumexp.
//
// Deadlock-free: producers never wait; only 32/2048 blocks wait; spins bounded.
// ---------------------------------------------------------------------------
__global__ __launch_bounds__(256, 8) void fused_kernel(
    const float* __restrict__ x,
    const float* __restrict__ w,
    const float* __restrict__ conv_bias,
    const float* __restrict__ extra_bias,
    unsigned long long* __restrict__ Sx64,
    unsigned long long* __restrict__ Sw64,
    float* __restrict__ out)
{
    const int b = blockIdx.x;
    const int t = threadIdx.x;

    __shared__ float sws_odd[32][COUT];   // 16 KB: Sw[ci=2k+1][co]
    __shared__ float sxs[CIN];
    __shared__ float part[4];
    __shared__ float wm[4], wl[4];

    // ---- Sw chunk (blocks 0..31, published before anything else)
    if (b < 32) {
        const int o = b * 256 + t;                   // 0..8191 = ci*128+co
        const float4* wp = (const float4*)(w + (size_t)o * 16);
        float4 a = wp[0], c = wp[1], d = wp[2], e = wp[3];
        const float sw =
            (((a.x + a.y) + (a.z + a.w)) + ((c.x + c.y) + (c.z + c.w))) +
            (((d.x + d.y) + (d.z + d.w)) + ((e.x + e.y) + (e.z + e.w)));
        const unsigned long long word =
            ((unsigned long long)MAGIC << 32) | (unsigned long long)__float_as_uint(sw);
        __hip_atomic_exchange(&Sw64[o], word, __ATOMIC_RELAXED,
                              __HIP_MEMORY_SCOPE_AGENT);
    }

    // ---- Phase A: one x-plane sum per block (exact R0 tree), publish 1 word
    {
        const float4* xp = (const float4*)(x + (size_t)b * HWVOL);
        float acc = 0.0f;
#pragma unroll
        for (int j = 0; j < 4; ++j) {
            float4 v = xp[t + 256 * j];
            acc += (v.x + v.y) + (v.z + v.w);
        }
#pragma unroll
        for (int off = 32; off > 0; off >>= 1)
            acc += __shfl_down(acc, off, 64);
        if ((t & 63) == 0) part[t >> 6] = acc;
        __syncthreads();
        if (t == 0) {
            const float s = (part[0] + part[1]) + (part[2] + part[3]);
            const unsigned long long word =
                ((unsigned long long)MAGIC << 32) | (unsigned long long)__float_as_uint(s);
            __hip_atomic_exchange(&Sx64[b], word, __ATOMIC_RELAXED,
                                  __HIP_MEMORY_SCOPE_AGENT);
        }
    }

    // ---- Phase B: blocks 0..31 consume; block n -> out[n]
    if (b >= Nn) return;
    const int n = b;
    const int co = t & 127;

    // Poll the 64 plane words of image n (agent atomic loads: coherent + cheap)
    if (t < CIN) {
        const int idx = n * CIN + t;
        unsigned long long word;
        int spins = 0;
        for (;;) {
            word = __hip_atomic_load(&Sx64[idx], __ATOMIC_RELAXED,
                                     __HIP_MEMORY_SCOPE_AGENT);
            if ((unsigned)(word >> 32) == MAGIC) break;
            __builtin_amdgcn_s_sleep(1);
            if (++spins > (1 << 18)) break;   // bounded: fail loudly, never hang
        }
        sxs[t] = __uint_as_float((unsigned)word);
    }

    // Cooperative Sw fetch: batches of 8 independent atomic loads (pipelined).
    float sw_reg[32];                          // even-ci values for t<128
#pragma unroll
    for (int g = 0; g < 4; ++g) {
        unsigned long long wb[8];
#pragma unroll
        for (int j = 0; j < 8; ++j)
            wb[j] = __hip_atomic_load(&Sw64[(g * 8 + j) * 256 + t],
                                      __ATOMIC_RELAXED, __HIP_MEMORY_SCOPE_AGENT);
#pragma unroll
        for (int j = 0; j < 8; ++j) {
            int spins = 0;
            while ((unsigned)(wb[j] >> 32) != MAGIC) {   // almost never taken
                __builtin_amdgcn_s_sleep(1);
                wb[j] = __hip_atomic_load(&Sw64[(g * 8 + j) * 256 + t],
                                          __ATOMIC_RELAXED, __HIP_MEMORY_SCOPE_AGENT);
                if (++spins > (1 << 18)) break;
            }
            const float v = __uint_as_float((unsigned)wb[j]);
            if (t < 128) sw_reg[g * 8 + j] = v;          // ci = 2(g*8+j)
            else         sws_odd[g * 8 + j][co] = v;     // ci = 2(g*8+j)+1
        }
    }
    __syncthreads();

    // GEMV in EXACT ci = 0..63 sequential order (bit-identical to R0 kernel)
    float pooled = NEGBIG;
    if (t < COUT) {
        float acc = 0.0f;
#pragma unroll
        for (int k = 0; k < 32; ++k) {
            acc = fmaf(sxs[2 * k],     sw_reg[k],       acc);   // even ci
            acc = fmaf(sxs[2 * k + 1], sws_odd[k][co],  acc);   // odd  ci
        }
        pooled = acc * OHW_INV + conv_bias[co] + extra_bias[co];
    }

    // logsumexp across 128 live lanes (4 waves; waves 2,3 hold NEGBIG -> exp->0)
    float m = pooled;
#pragma unroll
    for (int off = 32; off > 0; off >>= 1)
        m = fmaxf(m, __shfl_xor(m, off, 64));
    if ((t & 63) == 0) wm[t >> 6] = m;
    __syncthreads();
    m = fmaxf(fmaxf(wm[0], wm[1]), fmaxf(wm[2], wm[3]));

    float e = __expf(pooled - m);
#pragma unroll
    for (int off = 32; off > 0; off >>= 1)
        e += __shfl_xor(e, off, 64);
    if ((t & 63) == 0) wl[t >> 6] = e;
    __syncthreads();
    if (t == 0) out[n] = 10.0f * (m + logf((wl[0] + wl[1]) + (wl[2] + wl[3])));
}

extern "C" void kernel_launch(void* const* d_in, const int* in_sizes, int n_in,
                              void* d_out, int out_size, void* d_ws, size_t ws_size,
                              hipStream_t stream) {
    const float* x          = (const float*)d_in[0];
    const float* weight     = (const float*)d_in[1];
    const float* conv_bias  = (const float*)d_in[2];
    const float* extra_bias = (const float*)d_in[3];
    float* out = (float*)d_out;

    unsigned long long* Sx64 = (unsigned long long*)d_ws;   // 2048 u64
    unsigned long long* Sw64 = Sx64 + PLANES;               // 8192 u64

    fused_kernel<<<PLANES, 256, 0, stream>>>(x, weight, conv_bias, extra_bias,
                                             Sx64, Sw64, out);
}